// Round 4
// baseline (56.481 us; speedup 1.0000x reference)
//
#include <hip/hip_runtime.h>
#include <stdint.h>

typedef short bf16x8 __attribute__((ext_vector_type(8)));
typedef float f32x16 __attribute__((ext_vector_type(16)));
typedef unsigned short ushort_t;

#define NTOK 16384   // 32*512
#define EMB 256
#define HID 1024

// ---------------- ws layout ----------------
// Af: fragment-ordered A  [512 grp][16 ks][64 lane][8 elem] bf16 = 8 MB
// Wf: fragment-ordered Wb [ 32 grp][16 ks][64 lane][8 elem] bf16 = 512 KB
#define WS_A_OFF   0
#define WS_W_OFF   (8u * 1024u * 1024u)
#define WS_F_OFF   (WS_W_OFF + 512u * 1024u)

// ---------------- SHA-256/224 with zero arrays (rule #20 safe) ----------------
#define ROTR(x,n) (((x)>>(n))|((x)<<(32-(n))))
#define S0F(x) (ROTR((x),7)^ROTR((x),18)^((x)>>3))
#define S1F(x) (ROTR((x),17)^ROTR((x),19)^((x)>>10))

#define RND2(Kc, Wt) do {                                                         \
    const uint32_t kw_ = (Kc) + (Wt);                                             \
    uint32_t t1_ = h0 + (ROTR(e0,6)^ROTR(e0,11)^ROTR(e0,25))                      \
                   + ((e0&f0)^(~e0&g0)) + kw_;                                    \
    uint32_t t2_ = (ROTR(a0,2)^ROTR(a0,13)^ROTR(a0,22))                           \
                   + ((a0&b0)^(a0&c0)^(b0&c0));                                   \
    h0=g0; g0=f0; f0=e0; e0=d0+t1_; d0=c0; c0=b0; b0=a0; a0=t1_+t2_;              \
    uint32_t u1_ = h1 + (ROTR(e1,6)^ROTR(e1,11)^ROTR(e1,25))                      \
                   + ((e1&f1)^(~e1&g1)) + kw_;                                    \
    uint32_t u2_ = (ROTR(a1,2)^ROTR(a1,13)^ROTR(a1,22))                           \
                   + ((a1&b1)^(a1&c1)^(b1&c1));                                   \
    h1=g1; g1=f1; f1=e1; e1=d1+u1_; d1=c1; c1=b1; b1=a1; a1=u1_+u2_;              \
} while (0)

// rolling schedule step: a += s0(b) + c + s1(d)
#define WSX(a,b,c,d) ((a) += S0F(b) + (c) + S1F(d))

#define STAGE16_UNUSED 0

// Detect int32 vs int64 layout of input_ids. Reads only the guaranteed 64KB
// (as uint4); if int64 little-endian, words 1,3 of every uint4 are zero.
__global__ __launch_bounds__(64) void detect_kernel(const uint4* __restrict__ ids4,
                                                    uint32_t* __restrict__ flag) {
    uint32_t acc = 0;
    for (int i = threadIdx.x; i < 4096; i += 64) {
        uint4 v = ids4[i];
        acc |= v.y | v.w;
    }
    unsigned long long m = __ballot(acc != 0);
    if (threadIdx.x == 0) *flag = (m == 0ull) ? 1u : 0u;
}

// Per thread t in [0,16384):
//  - SHA-256 + SHA-224 first digest byte of str(ids[t]) -> A-row in fragment order
//  - W chunk (h = t>>4, kk = t&15): 16 floats -> bf16 -> Wf in fragment order
__global__ __launch_bounds__(64) void prep_kernel(const uint32_t* __restrict__ ids32,
                                                  const uint32_t* __restrict__ flag,
                                                  ushort_t* __restrict__ Af,
                                                  const float* __restrict__ W,
                                                  ushort_t* __restrict__ Wf) {
    const int t = blockIdx.x * 64 + threadIdx.x;

    // ---- issue W loads early (16 floats, coalesced 64B/thread) ----
    const int h = t >> 4;
    const int kk = t & 15;
    const float4* wsrc = reinterpret_cast<const float4*>(W + h * EMB + kk * 16);
    float4 wfa = wsrc[0], wfb = wsrc[1], wfc = wsrc[2], wfd = wsrc[3];

    uint32_t v;
    if (*flag) v = ids32[2 * t];
    else       v = ids32[t];

    // ---- branchless decimal digits (v < 32000 -> <=5 digits) ----
    const uint32_t q4 = __umulhi(v, 0xD1B71759u) >> 13;        // /10000
    const uint32_t r4 = v - q4 * 10000u;
    const uint32_t q3 = __umulhi(r4, 0x10624DD3u) >> 6;        // /1000
    const uint32_t r3 = r4 - q3 * 1000u;
    const uint32_t q2 = __umulhi(r3, 0x51EB851Fu) >> 5;        // /100
    const uint32_t r2 = r3 - q2 * 100u;
    const uint32_t q1 = __umulhi(r2, 0xCCCCCCCDu) >> 3;        // /10
    const uint32_t q0 = r2 - q1 * 10u;
    const uint32_t nd = v >= 10000u ? 5u : v >= 1000u ? 4u : v >= 100u ? 3u
                         : v >= 10u ? 2u : 1u;
    uint64_t M = ((uint64_t)(q4 + '0') << 56) | ((uint64_t)(q3 + '0') << 48) |
                 ((uint64_t)(q2 + '0') << 40) | ((uint64_t)(q1 + '0') << 32) |
                 ((uint64_t)(q0 + '0') << 24) | ((uint64_t)0x80u << 16);
    M <<= 8u * (5u - nd);   // drop leading '0' digits

    uint32_t w0 = (uint32_t)(M >> 32), w1 = (uint32_t)M;
    uint32_t w2 = 0, w3 = 0, w4 = 0, w5 = 0, w6 = 0, w7 = 0;
    uint32_t w8 = 0, w9 = 0, w10 = 0, w11 = 0, w12 = 0, w13 = 0, w14 = 0;
    uint32_t w15 = nd * 8u;

    uint32_t a0=0x6a09e667u,b0=0xbb67ae85u,c0=0x3c6ef372u,d0=0xa54ff53au,
             e0=0x510e527fu,f0=0x9b05688cu,g0=0x1f83d9abu,h0=0x5be0cd19u;
    uint32_t a1=0xc1059ed8u,b1=0x367cd507u,c1=0x3070dd17u,d1=0xf70e5939u,
             e1=0xffc00b31u,f1=0x68581511u,g1=0x64f98fa7u,h1=0xbefa4fa4u;

    // rounds 0-15
    RND2(0x428a2f98u, w0);  RND2(0x71374491u, w1);  RND2(0xb5c0fbcfu, w2);
    RND2(0xe9b5dba5u, w3);  RND2(0x3956c25bu, w4);  RND2(0x59f111f1u, w5);
    RND2(0x923f82a4u, w6);  RND2(0xab1c5ed5u, w7);  RND2(0xd807aa98u, w8);
    RND2(0x12835b01u, w9);  RND2(0x243185beu, w10); RND2(0x550c7dc3u, w11);
    RND2(0x72be5d74u, w12); RND2(0x80deb1feu, w13); RND2(0x9bdc06a7u, w14);
    RND2(0xc19bf174u, w15);
    // rounds 16-31
    WSX(w0,w1,w9,w14);    RND2(0xe49b69c1u, w0);
    WSX(w1,w2,w10,w15);   RND2(0xefbe4786u, w1);
    WSX(w2,w3,w11,w0);    RND2(0x0fc19dc6u, w2);
    WSX(w3,w4,w12,w1);    RND2(0x240ca1ccu, w3);
    WSX(w4,w5,w13,w2);    RND2(0x2de92c6fu, w4);
    WSX(w5,w6,w14,w3);    RND2(0x4a7484aau, w5);
    WSX(w6,w7,w15,w4);    RND2(0x5cb0a9dcu, w6);
    WSX(w7,w8,w0,w5);     RND2(0x76f988dau, w7);
    WSX(w8,w9,w1,w6);     RND2(0x983e5152u, w8);
    WSX(w9,w10,w2,w7);    RND2(0xa831c66du, w9);
    WSX(w10,w11,w3,w8);   RND2(0xb00327c8u, w10);
    WSX(w11,w12,w4,w9);   RND2(0xbf597fc7u, w11);
    WSX(w12,w13,w5,w10);  RND2(0xc6e00bf3u, w12);
    WSX(w13,w14,w6,w11);  RND2(0xd5a79147u, w13);
    WSX(w14,w15,w7,w12);  RND2(0x06ca6351u, w14);
    WSX(w15,w0,w8,w13);   RND2(0x14292967u, w15);
    // rounds 32-47
    WSX(w0,w1,w9,w14);    RND2(0x27b70a85u, w0);
    WSX(w1,w2,w10,w15);   RND2(0x2e1b2138u, w1);
    WSX(w2,w3,w11,w0);    RND2(0x4d2c6dfcu, w2);
    WSX(w3,w4,w12,w1);    RND2(0x53380d13u, w3);
    WSX(w4,w5,w13,w2);    RND2(0x650a7354u, w4);
    WSX(w5,w6,w14,w3);    RND2(0x766a0abbu, w5);
    WSX(w6,w7,w15,w4);    RND2(0x81c2c92eu, w6);
    WSX(w7,w8,w0,w5);     RND2(0x92722c85u, w7);
    WSX(w8,w9,w1,w6);     RND2(0xa2bfe8a1u, w8);
    WSX(w9,w10,w2,w7);    RND2(0xa81a664bu, w9);
    WSX(w10,w11,w3,w8);   RND2(0xc24b8b70u, w10);
    WSX(w11,w12,w4,w9);   RND2(0xc76c51a3u, w11);
    WSX(w12,w13,w5,w10);  RND2(0xd192e819u, w12);
    WSX(w13,w14,w6,w11);  RND2(0xd6990624u, w13);
    WSX(w14,w15,w7,w12);  RND2(0xf40e3585u, w14);
    WSX(w15,w0,w8,w13);   RND2(0x106aa070u, w15);
    // rounds 48-63
    WSX(w0,w1,w9,w14);    RND2(0x19a4c116u, w0);
    WSX(w1,w2,w10,w15);   RND2(0x1e376c08u, w1);
    WSX(w2,w3,w11,w0);    RND2(0x2748774cu, w2);
    WSX(w3,w4,w12,w1);    RND2(0x34b0bcb5u, w3);
    WSX(w4,w5,w13,w2);    RND2(0x391c0cb3u, w4);
    WSX(w5,w6,w14,w3);    RND2(0x4ed8aa4au, w5);
    WSX(w6,w7,w15,w4);    RND2(0x5b9cca4fu, w6);
    WSX(w7,w8,w0,w5);     RND2(0x682e6ff3u, w7);
    WSX(w8,w9,w1,w6);     RND2(0x748f82eeu, w8);
    WSX(w9,w10,w2,w7);    RND2(0x78a5636fu, w9);
    WSX(w10,w11,w3,w8);   RND2(0x84c87814u, w10);
    WSX(w11,w12,w4,w9);   RND2(0x8cc70208u, w11);
    WSX(w12,w13,w5,w10);  RND2(0x90befffau, w12);
    WSX(w13,w14,w6,w11);  RND2(0xa4506cebu, w13);
    WSX(w14,w15,w7,w12);  RND2(0xbef9a3f7u, w14);
    WSX(w15,w0,w8,w13);   RND2(0xc67178f2u, w15);

    const uint32_t hv1 = (0x6a09e667u + a0) >> 24;  // sha256 digest byte 0
    const uint32_t hv2 = (0xc1059ed8u + a1) >> 24;  // sha224 digest byte 0

    // ---- A-row in fragment order: Af[g=t>>5][ks][lane][8] ----
    // Af(g,ks,lane,j) = row(g*32+(lane&31))[ks*16+(lane>>5)*8+j]
    uint4* abase = reinterpret_cast<uint4*>(Af) + ((size_t)(t >> 5) * 16) * 64 + (t & 31);
    uint32_t val_ = hv1 & 255u;
#define PAIR(dst) { uint32_t lo_ = val_; uint32_t hi_ = (val_ + hv2) & 255u;      \
                    val_ = (hi_ + hv2) & 255u;                                    \
                    dst = (__float_as_uint((float)lo_) >> 16) |                   \
                          (__float_as_uint((float)hi_) & 0xFFFF0000u); }
#pragma unroll
    for (int ks = 0; ks < 16; ++ks) {
        uint32_t c0_, c1_, c2_, c3_, c4_, c5_, c6_, c7_;
        PAIR(c0_); PAIR(c1_); PAIR(c2_); PAIR(c3_);
        PAIR(c4_); PAIR(c5_); PAIR(c6_); PAIR(c7_);
        uint4 qa; qa.x = c0_; qa.y = c1_; qa.z = c2_; qa.w = c3_;
        uint4 qb; qb.x = c4_; qb.y = c5_; qb.z = c6_; qb.w = c7_;
        abase[ks * 64]      = qa;   // lane = t&31       (k-half 0)
        abase[ks * 64 + 32] = qb;   // lane = 32+(t&31)  (k-half 1)
    }
#undef PAIR

    // ---- W chunk -> bf16 (RNE) -> Wf[h>>5][kk][lane][8] ----
    auto rb = [](float x) -> uint32_t {
        uint32_t b = __float_as_uint(x);
        return (b + 0x7FFFu + ((b >> 16) & 1u)) >> 16;
    };
    uint4 qa, qb;
    qa.x = rb(wfa.x) | (rb(wfa.y) << 16);
    qa.y = rb(wfa.z) | (rb(wfa.w) << 16);
    qa.z = rb(wfb.x) | (rb(wfb.y) << 16);
    qa.w = rb(wfb.z) | (rb(wfb.w) << 16);
    qb.x = rb(wfc.x) | (rb(wfc.y) << 16);
    qb.y = rb(wfc.z) | (rb(wfc.w) << 16);
    qb.z = rb(wfd.x) | (rb(wfd.y) << 16);
    qb.w = rb(wfd.z) | (rb(wfd.w) << 16);
    uint4* wbase = reinterpret_cast<uint4*>(Wf) + ((size_t)(h >> 5) * 16 + kk) * 64 + (h & 31);
    wbase[0]  = qa;   // k-half 0
    wbase[32] = qb;   // k-half 1
}

// LDS-free GEMM: every fragment load is a wave-contiguous 1KB dwordx4 burst.
// Block 256 = 4 waves (2x2), wave tile 64x64, mfma_f32_32x32x16_bf16.
__global__ __launch_bounds__(256) void gemm_kernel(const ushort_t* __restrict__ Af,
                                                   const ushort_t* __restrict__ Wf,
                                                   const float* __restrict__ bias,
                                                   float* __restrict__ out) {
    // XCD-aware bijective swizzle (1024 blocks, 1024%8==0)
    const int bid0 = blockIdx.x;
    const int bid = (bid0 & 7) * 128 + (bid0 >> 3);
    const int bn = bid & 7;
    const int bm = bid >> 3;
    const int tid = (int)threadIdx.x;
    const int wv = tid >> 6;
    const int lane = tid & 63;
    const int lrow = lane & 31;
    const int lh = lane >> 5;

    const int m0 = bm * 128 + (wv >> 1) * 64;
    const int n0 = bn * 128 + (wv & 1) * 64;

    const bf16x8* pa = reinterpret_cast<const bf16x8*>(Af) + ((size_t)(m0 >> 5) * 16) * 64 + lane;
    const bf16x8* pb = reinterpret_cast<const bf16x8*>(Wf) + ((size_t)(n0 >> 5) * 16) * 64 + lane;

    f32x16 acc00 = {}, acc01 = {}, acc10 = {}, acc11 = {};
#pragma unroll 2
    for (int ks = 0; ks < 16; ++ks) {
        bf16x8 av0 = pa[ks * 64];          // group m0>>5
        bf16x8 av1 = pa[ks * 64 + 1024];   // group m0>>5 + 1 (rows +32)
        bf16x8 bv0 = pb[ks * 64];
        bf16x8 bv1 = pb[ks * 64 + 1024];
        acc00 = __builtin_amdgcn_mfma_f32_32x32x16_bf16(av0, bv0, acc00, 0, 0, 0);
        acc01 = __builtin_amdgcn_mfma_f32_32x32x16_bf16(av0, bv1, acc01, 0, 0, 0);
        acc10 = __builtin_amdgcn_mfma_f32_32x32x16_bf16(av1, bv0, acc10, 0, 0, 0);
        acc11 = __builtin_amdgcn_mfma_f32_32x32x16_bf16(av1, bv1, acc11, 0, 0, 0);
    }

    const float bj0 = bias[n0 + lrow];
    const float bj1 = bias[n0 + 32 + lrow];
#pragma unroll
    for (int r = 0; r < 16; ++r) {
        const int rowl = (r & 3) + 8 * (r >> 2) + 4 * lh;  // verified C/D layout
        const size_t off0 = (size_t)(m0 + rowl) * HID;
        const size_t off1 = (size_t)(m0 + 32 + rowl) * HID;
        out[off0 + n0 + lrow]      = acc00[r] + bj0;
        out[off0 + n0 + 32 + lrow] = acc01[r] + bj1;
        out[off1 + n0 + lrow]      = acc10[r] + bj0;
        out[off1 + n0 + 32 + lrow] = acc11[r] + bj1;
    }
}

extern "C" void kernel_launch(void* const* d_in, const int* in_sizes, int n_in,
                              void* d_out, int out_size, void* d_ws, size_t ws_size,
                              hipStream_t stream) {
    const uint32_t* ids32 = (const uint32_t*)d_in[0];
    const float* W = (const float*)d_in[1];
    const float* bias = (const float*)d_in[2];
    float* out = (float*)d_out;

    ushort_t* Af = (ushort_t*)((char*)d_ws + WS_A_OFF);
    ushort_t* Wf = (ushort_t*)((char*)d_ws + WS_W_OFF);
    uint32_t* flag = (uint32_t*)((char*)d_ws + WS_F_OFF);

    detect_kernel<<<1, 64, 0, stream>>>((const uint4*)ids32, flag);
    prep_kernel<<<NTOK / 64, 64, 0, stream>>>(ids32, flag, Af, W, Wf);
    gemm_kernel<<<(NTOK / 128) * (HID / 128), 256, 0, stream>>>(Af, Wf, bias, out);
}

// Round 5
// 39.390 us; speedup vs baseline: 1.4339x; 1.4339x over previous
//
#include <hip/hip_runtime.h>
#include <stdint.h>

typedef short bf16x8 __attribute__((ext_vector_type(8)));
typedef float f32x16 __attribute__((ext_vector_type(16)));
typedef unsigned short ushort_t;

#define NTOK 16384   // 32*512
#define EMB 256
#define HID 1024

// ---------------- ws layout ----------------
// Af: fragment-ordered A  [512 grp][16 ks][64 lane][8 elem] bf16 = 8 MB
// Wf: fragment-ordered Wb [ 32 grp][16 ks][64 lane][8 elem] bf16 = 512 KB
#define WS_A_OFF   0
#define WS_W_OFF   (8u * 1024u * 1024u)
#define WS_F_OFF   (WS_W_OFF + 512u * 1024u)

#define STAGE16(gsrc, ldsdst)                                                        \
    __builtin_amdgcn_global_load_lds(                                                \
        (const __attribute__((address_space(1))) void*)(gsrc),                       \
        (__attribute__((address_space(3))) void*)(ldsdst), 16, 0, 0)

// ---------------- SHA-256/224 with zero arrays (rule #20 safe) ----------------
#define ROTR(x,n) (((x)>>(n))|((x)<<(32-(n))))
#define S0F(x) (ROTR((x),7)^ROTR((x),18)^((x)>>3))
#define S1F(x) (ROTR((x),17)^ROTR((x),19)^((x)>>10))

#define RND2(Kc, Wt) do {                                                         \
    const uint32_t kw_ = (Kc) + (Wt);                                             \
    uint32_t t1_ = h0 + (ROTR(e0,6)^ROTR(e0,11)^ROTR(e0,25))                      \
                   + ((e0&f0)^(~e0&g0)) + kw_;                                    \
    uint32_t t2_ = (ROTR(a0,2)^ROTR(a0,13)^ROTR(a0,22))                           \
                   + ((a0&b0)^(a0&c0)^(b0&c0));                                   \
    h0=g0; g0=f0; f0=e0; e0=d0+t1_; d0=c0; c0=b0; b0=a0; a0=t1_+t2_;              \
    uint32_t u1_ = h1 + (ROTR(e1,6)^ROTR(e1,11)^ROTR(e1,25))                      \
                   + ((e1&f1)^(~e1&g1)) + kw_;                                    \
    uint32_t u2_ = (ROTR(a1,2)^ROTR(a1,13)^ROTR(a1,22))                           \
                   + ((a1&b1)^(a1&c1)^(b1&c1));                                   \
    h1=g1; g1=f1; f1=e1; e1=d1+u1_; d1=c1; c1=b1; b1=a1; a1=u1_+u2_;              \
} while (0)

#define WSX(a,b,c,d) ((a) += S0F(b) + (c) + S1F(d))

// Detect int32 vs int64 layout of input_ids. Scans the guaranteed 64KB as
// uint4 with 1024 threads x 4 loads; int64 LE => words y,w of every uint4 == 0.
__global__ __launch_bounds__(1024) void detect_kernel(const uint4* __restrict__ ids4,
                                                      uint32_t* __restrict__ flag) {
    __shared__ uint32_t red[16];
    const int tid = (int)threadIdx.x;
    uint32_t acc = 0;
#pragma unroll
    for (int i = 0; i < 4; ++i) {
        uint4 v = ids4[tid + i * 1024];
        acc |= v.y | v.w;
    }
    unsigned long long m = __ballot(acc != 0u);
    if ((tid & 63) == 0) red[tid >> 6] = (m != 0ull) ? 1u : 0u;
    __syncthreads();
    if (tid < 64) {
        uint32_t r = (tid < 16) ? red[tid] : 0u;
        unsigned long long mm = __ballot(r != 0u);
        if (tid == 0) *flag = (mm == 0ull) ? 1u : 0u;
    }
}

// Per thread t in [0,16384):
//  - SHA-256 + SHA-224 first digest byte of str(ids[t]) -> A-row in fragment order
//  - W chunk (h = t>>4, kk = t&15): 16 floats -> bf16 -> Wf in fragment order
__global__ __launch_bounds__(64) void prep_kernel(const uint32_t* __restrict__ ids32,
                                                  const uint32_t* __restrict__ flag,
                                                  ushort_t* __restrict__ Af,
                                                  const float* __restrict__ W,
                                                  ushort_t* __restrict__ Wf) {
    const int t = blockIdx.x * 64 + threadIdx.x;

    // ---- issue W loads early (16 floats per thread) ----
    const int h = t >> 4;
    const int kk = t & 15;
    const float4* wsrc = reinterpret_cast<const float4*>(W + h * EMB + kk * 16);
    float4 wfa = wsrc[0], wfb = wsrc[1], wfc = wsrc[2], wfd = wsrc[3];

    uint32_t v;
    if (*flag) v = ids32[2 * t];
    else       v = ids32[t];

    // ---- branchless decimal digits (v < 32000 -> <=5 digits) ----
    const uint32_t q4 = __umulhi(v, 0xD1B71759u) >> 13;        // /10000
    const uint32_t r4 = v - q4 * 10000u;
    const uint32_t q3 = __umulhi(r4, 0x10624DD3u) >> 6;        // /1000
    const uint32_t r3 = r4 - q3 * 1000u;
    const uint32_t q2 = __umulhi(r3, 0x51EB851Fu) >> 5;        // /100
    const uint32_t r2 = r3 - q2 * 100u;
    const uint32_t q1 = __umulhi(r2, 0xCCCCCCCDu) >> 3;        // /10
    const uint32_t q0 = r2 - q1 * 10u;
    const uint32_t nd = v >= 10000u ? 5u : v >= 1000u ? 4u : v >= 100u ? 3u
                         : v >= 10u ? 2u : 1u;
    uint64_t M = ((uint64_t)(q4 + '0') << 56) | ((uint64_t)(q3 + '0') << 48) |
                 ((uint64_t)(q2 + '0') << 40) | ((uint64_t)(q1 + '0') << 32) |
                 ((uint64_t)(q0 + '0') << 24) | ((uint64_t)0x80u << 16);
    M <<= 8u * (5u - nd);   // drop leading '0' digits

    uint32_t w0 = (uint32_t)(M >> 32), w1 = (uint32_t)M;
    uint32_t w2 = 0, w3 = 0, w4 = 0, w5 = 0, w6 = 0, w7 = 0;
    uint32_t w8 = 0, w9 = 0, w10 = 0, w11 = 0, w12 = 0, w13 = 0, w14 = 0;
    uint32_t w15 = nd * 8u;

    uint32_t a0=0x6a09e667u,b0=0xbb67ae85u,c0=0x3c6ef372u,d0=0xa54ff53au,
             e0=0x510e527fu,f0=0x9b05688cu,g0=0x1f83d9abu,h0=0x5be0cd19u;
    uint32_t a1=0xc1059ed8u,b1=0x367cd507u,c1=0x3070dd17u,d1=0xf70e5939u,
             e1=0xffc00b31u,f1=0x68581511u,g1=0x64f98fa7u,h1=0xbefa4fa4u;

    // rounds 0-15
    RND2(0x428a2f98u, w0);  RND2(0x71374491u, w1);  RND2(0xb5c0fbcfu, w2);
    RND2(0xe9b5dba5u, w3);  RND2(0x3956c25bu, w4);  RND2(0x59f111f1u, w5);
    RND2(0x923f82a4u, w6);  RND2(0xab1c5ed5u, w7);  RND2(0xd807aa98u, w8);
    RND2(0x12835b01u, w9);  RND2(0x243185beu, w10); RND2(0x550c7dc3u, w11);
    RND2(0x72be5d74u, w12); RND2(0x80deb1feu, w13); RND2(0x9bdc06a7u, w14);
    RND2(0xc19bf174u, w15);
    // rounds 16-31
    WSX(w0,w1,w9,w14);    RND2(0xe49b69c1u, w0);
    WSX(w1,w2,w10,w15);   RND2(0xefbe4786u, w1);
    WSX(w2,w3,w11,w0);    RND2(0x0fc19dc6u, w2);
    WSX(w3,w4,w12,w1);    RND2(0x240ca1ccu, w3);
    WSX(w4,w5,w13,w2);    RND2(0x2de92c6fu, w4);
    WSX(w5,w6,w14,w3);    RND2(0x4a7484aau, w5);
    WSX(w6,w7,w15,w4);    RND2(0x5cb0a9dcu, w6);
    WSX(w7,w8,w0,w5);     RND2(0x76f988dau, w7);
    WSX(w8,w9,w1,w6);     RND2(0x983e5152u, w8);
    WSX(w9,w10,w2,w7);    RND2(0xa831c66du, w9);
    WSX(w10,w11,w3,w8);   RND2(0xb00327c8u, w10);
    WSX(w11,w12,w4,w9);   RND2(0xbf597fc7u, w11);
    WSX(w12,w13,w5,w10);  RND2(0xc6e00bf3u, w12);
    WSX(w13,w14,w6,w11);  RND2(0xd5a79147u, w13);
    WSX(w14,w15,w7,w12);  RND2(0x06ca6351u, w14);
    WSX(w15,w0,w8,w13);   RND2(0x14292967u, w15);
    // rounds 32-47
    WSX(w0,w1,w9,w14);    RND2(0x27b70a85u, w0);
    WSX(w1,w2,w10,w15);   RND2(0x2e1b2138u, w1);
    WSX(w2,w3,w11,w0);    RND2(0x4d2c6dfcu, w2);
    WSX(w3,w4,w12,w1);    RND2(0x53380d13u, w3);
    WSX(w4,w5,w13,w2);    RND2(0x650a7354u, w4);
    WSX(w5,w6,w14,w3);    RND2(0x766a0abbu, w5);
    WSX(w6,w7,w15,w4);    RND2(0x81c2c92eu, w6);
    WSX(w7,w8,w0,w5);     RND2(0x92722c85u, w7);
    WSX(w8,w9,w1,w6);     RND2(0xa2bfe8a1u, w8);
    WSX(w9,w10,w2,w7);    RND2(0xa81a664bu, w9);
    WSX(w10,w11,w3,w8);   RND2(0xc24b8b70u, w10);
    WSX(w11,w12,w4,w9);   RND2(0xc76c51a3u, w11);
    WSX(w12,w13,w5,w10);  RND2(0xd192e819u, w12);
    WSX(w13,w14,w6,w11);  RND2(0xd6990624u, w13);
    WSX(w14,w15,w7,w12);  RND2(0xf40e3585u, w14);
    WSX(w15,w0,w8,w13);   RND2(0x106aa070u, w15);
    // rounds 48-63
    WSX(w0,w1,w9,w14);    RND2(0x19a4c116u, w0);
    WSX(w1,w2,w10,w15);   RND2(0x1e376c08u, w1);
    WSX(w2,w3,w11,w0);    RND2(0x2748774cu, w2);
    WSX(w3,w4,w12,w1);    RND2(0x34b0bcb5u, w3);
    WSX(w4,w5,w13,w2);    RND2(0x391c0cb3u, w4);
    WSX(w5,w6,w14,w3);    RND2(0x4ed8aa4au, w5);
    WSX(w6,w7,w15,w4);    RND2(0x5b9cca4fu, w6);
    WSX(w7,w8,w0,w5);     RND2(0x682e6ff3u, w7);
    WSX(w8,w9,w1,w6);     RND2(0x748f82eeu, w8);
    WSX(w9,w10,w2,w7);    RND2(0x78a5636fu, w9);
    WSX(w10,w11,w3,w8);   RND2(0x84c87814u, w10);
    WSX(w11,w12,w4,w9);   RND2(0x8cc70208u, w11);
    WSX(w12,w13,w5,w10);  RND2(0x90befffau, w12);
    WSX(w13,w14,w6,w11);  RND2(0xa4506cebu, w13);
    WSX(w14,w15,w7,w12);  RND2(0xbef9a3f7u, w14);
    WSX(w15,w0,w8,w13);   RND2(0xc67178f2u, w15);

    const uint32_t hv1 = (0x6a09e667u + a0) >> 24;  // sha256 digest byte 0
    const uint32_t hv2 = (0xc1059ed8u + a1) >> 24;  // sha224 digest byte 0

    // ---- A-row in fragment order: Af[g=t>>5][ks][lane][8] ----
    // Af(g,ks,lane,j) = row(g*32+(lane&31))[ks*16+(lane>>5)*8+j]
    uint4* abase = reinterpret_cast<uint4*>(Af) + ((size_t)(t >> 5) * 16) * 64 + (t & 31);
    uint32_t val_ = hv1 & 255u;
#define PAIR(dst) { uint32_t lo_ = val_; uint32_t hi_ = (val_ + hv2) & 255u;      \
                    val_ = (hi_ + hv2) & 255u;                                    \
                    dst = (__float_as_uint((float)lo_) >> 16) |                   \
                          (__float_as_uint((float)hi_) & 0xFFFF0000u); }
#pragma unroll
    for (int ks = 0; ks < 16; ++ks) {
        uint32_t c0_, c1_, c2_, c3_, c4_, c5_, c6_, c7_;
        PAIR(c0_); PAIR(c1_); PAIR(c2_); PAIR(c3_);
        PAIR(c4_); PAIR(c5_); PAIR(c6_); PAIR(c7_);
        uint4 qa; qa.x = c0_; qa.y = c1_; qa.z = c2_; qa.w = c3_;
        uint4 qb; qb.x = c4_; qb.y = c5_; qb.z = c6_; qb.w = c7_;
        abase[ks * 64]      = qa;   // lane = t&31       (k-half 0)
        abase[ks * 64 + 32] = qb;   // lane = 32+(t&31)  (k-half 1)
    }
#undef PAIR

    // ---- W chunk -> bf16 (RNE) -> Wf[h>>5][kk][lane][8] ----
    auto rb = [](float x) -> uint32_t {
        uint32_t b = __float_as_uint(x);
        return (b + 0x7FFFu + ((b >> 16) & 1u)) >> 16;
    };
    uint4 qa, qb;
    qa.x = rb(wfa.x) | (rb(wfa.y) << 16);
    qa.y = rb(wfa.z) | (rb(wfa.w) << 16);
    qa.z = rb(wfb.x) | (rb(wfb.y) << 16);
    qa.w = rb(wfb.z) | (rb(wfb.w) << 16);
    qb.x = rb(wfc.x) | (rb(wfc.y) << 16);
    qb.y = rb(wfc.z) | (rb(wfc.w) << 16);
    qb.z = rb(wfd.x) | (rb(wfd.y) << 16);
    qb.w = rb(wfd.z) | (rb(wfd.w) << 16);
    uint4* wbase = reinterpret_cast<uint4*>(Wf) + ((size_t)(h >> 5) * 16 + kk) * 64 + (h & 31);
    wbase[0]  = qa;   // k-half 0
    wbase[32] = qb;   // k-half 1
}

// GEMM: block tile 128x128, K=256 in TWO LDS phases of K=128 (32KB A + 32KB B
// per phase, 64KB total -> 2 blocks/CU). Data is ALREADY in fragment order, so
// staging is linear-contiguous on both sides (no swizzle) and every
// ds_read_b128 is lane-contiguous (bank-conflict-free by construction).
// 4 waves (2x2), wave tile 64x64, mfma_f32_32x32x16_bf16.
__global__ __launch_bounds__(256, 2) void gemm_kernel(const ushort_t* __restrict__ Af,
                                                      const ushort_t* __restrict__ Wf,
                                                      const float* __restrict__ bias,
                                                      float* __restrict__ out) {
    __shared__ uint4 AbV[2048];   // 32KB: [4 grp][8 ks][64 lane] x 16B
    __shared__ uint4 BbV[2048];   // 32KB
    char* Ab = (char*)AbV;
    char* Bb = (char*)BbV;

    // XCD-aware bijective swizzle (1024 blocks, 1024%8==0)
    const int bid0 = blockIdx.x;
    const int bid = (bid0 & 7) * 128 + (bid0 >> 3);
    const int bn = bid & 7;
    const int bm = bid >> 3;
    const int tid = (int)threadIdx.x;
    const int wv = tid >> 6;
    const int lane = tid & 63;
    const int lrow = lane & 31;
    const int lh = lane >> 5;

    const char* Asrc = (const char*)Af + (size_t)bm * 4 * 16 * 1024;  // block's 4 m-groups
    const char* Bsrc = (const char*)Wf + (size_t)bn * 4 * 16 * 1024;  // block's 4 n-groups

    const int m0 = bm * 128 + (wv >> 1) * 64;
    const int n0 = bn * 128 + (wv & 1) * 64;
    const int lga = (wv >> 1) * 2;   // local m-group of this wave (0 or 2)
    const int lgb = (wv & 1) * 2;    // local n-group

    // issue bias loads early; they sit in regs until the epilogue
    const float bj0 = bias[n0 + lrow];
    const float bj1 = bias[n0 + 32 + lrow];

    f32x16 acc00 = {}, acc01 = {}, acc10 = {}, acc11 = {};

    for (int ph = 0; ph < 2; ++ph) {
        // ---- stage one K-half: 32 A-chunks + 32 B-chunks of 1KB, 8 each per wave ----
#pragma unroll
        for (int j = 0; j < 8; ++j) {
            const int c = j * 4 + wv;           // chunk 0..31
            const int grp = c >> 3;
            const int ks = c & 7;
            const size_t goff = ((size_t)grp * 16 + (size_t)ph * 8 + ks) * 1024 + (size_t)lane * 16;
            STAGE16(Asrc + goff, Ab + c * 1024);
            STAGE16(Bsrc + goff, Bb + c * 1024);
        }
        __syncthreads();   // drains vmcnt (global_load_lds) + barrier

        // ---- compute this K-half (8 ks steps) ----
#pragma unroll
        for (int ks = 0; ks < 8; ++ks) {
            bf16x8 av0 = *reinterpret_cast<const bf16x8*>(Ab + (((lga    ) * 8 + ks) * 64 + lane) * 16);
            bf16x8 av1 = *reinterpret_cast<const bf16x8*>(Ab + (((lga + 1) * 8 + ks) * 64 + lane) * 16);
            bf16x8 bv0 = *reinterpret_cast<const bf16x8*>(Bb + (((lgb    ) * 8 + ks) * 64 + lane) * 16);
            bf16x8 bv1 = *reinterpret_cast<const bf16x8*>(Bb + (((lgb + 1) * 8 + ks) * 64 + lane) * 16);
            acc00 = __builtin_amdgcn_mfma_f32_32x32x16_bf16(av0, bv0, acc00, 0, 0, 0);
            acc01 = __builtin_amdgcn_mfma_f32_32x32x16_bf16(av0, bv1, acc01, 0, 0, 0);
            acc10 = __builtin_amdgcn_mfma_f32_32x32x16_bf16(av1, bv0, acc10, 0, 0, 0);
            acc11 = __builtin_amdgcn_mfma_f32_32x32x16_bf16(av1, bv1, acc11, 0, 0, 0);
        }
        __syncthreads();   // all reads done before next phase overwrites
    }

#pragma unroll
    for (int r = 0; r < 16; ++r) {
        const int rowl = (r & 3) + 8 * (r >> 2) + 4 * lh;  // verified C/D layout
        const size_t off0 = (size_t)(m0 + rowl) * HID;
        const size_t off1 = (size_t)(m0 + 32 + rowl) * HID;
        out[off0 + n0 + lrow]      = acc00[r] + bj0;
        out[off0 + n0 + 32 + lrow] = acc01[r] + bj1;
        out[off1 + n0 + lrow]      = acc10[r] + bj0;
        out[off1 + n0 + 32 + lrow] = acc11[r] + bj1;
    }
}

extern "C" void kernel_launch(void* const* d_in, const int* in_sizes, int n_in,
                              void* d_out, int out_size, void* d_ws, size_t ws_size,
                              hipStream_t stream) {
    const uint32_t* ids32 = (const uint32_t*)d_in[0];
    const float* W = (const float*)d_in[1];
    const float* bias = (const float*)d_in[2];
    float* out = (float*)d_out;

    ushort_t* Af = (ushort_t*)((char*)d_ws + WS_A_OFF);
    ushort_t* Wf = (ushort_t*)((char*)d_ws + WS_W_OFF);
    uint32_t* flag = (uint32_t*)((char*)d_ws + WS_F_OFF);

    detect_kernel<<<1, 1024, 0, stream>>>((const uint4*)ids32, flag);
    prep_kernel<<<NTOK / 64, 64, 0, stream>>>(ids32, flag, Af, W, Wf);
    gemm_kernel<<<(NTOK / 128) * (HID / 128), 256, 0, stream>>>(Af, Wf, bias, out);
}

// Round 6
// 36.402 us; speedup vs baseline: 1.5516x; 1.0821x over previous
//
#include <hip/hip_runtime.h>
#include <stdint.h>

typedef short bf16x8 __attribute__((ext_vector_type(8)));
typedef float f32x16 __attribute__((ext_vector_type(16)));

#define EMB 256
#define HID 1024

// ---------------- SHA-256/224 primitives (proven in R4/R5) ----------------
#define ROTR(x,n) (((x)>>(n))|((x)<<(32-(n))))
#define S0F(x) (ROTR((x),7)^ROTR((x),18)^((x)>>3))
#define S1F(x) (ROTR((x),17)^ROTR((x),19)^((x)>>10))

// single-state round (state in sa..sh)
#define RND1(Kc, Wt) do {                                                          \
    uint32_t t1_ = sh + (ROTR(se,6)^ROTR(se,11)^ROTR(se,25))                       \
                   + ((se&sf)^(~se&sg)) + (Kc) + (Wt);                             \
    uint32_t t2_ = (ROTR(sa,2)^ROTR(sa,13)^ROTR(sa,22))                            \
                   + ((sa&sb)^(sa&sc)^(sb&sc));                                    \
    sh=sg; sg=sf; sf=se; se=sd+t1_; sd=sc; sc=sb; sb=sa; sa=t1_+t2_; } while (0)

#define WSXS(a,b,c,d) ((a) += S0F(b) + (c) + S1F(d))

__device__ __forceinline__ uint32_t rbf(float x) {
    uint32_t b = __float_as_uint(x);
    return (b + 0x7FFFu + ((b >> 16) & 1u)) >> 16;   // fp32 -> bf16 RNE
}
__device__ __forceinline__ uint4 pack8(float4 a, float4 b) {
    uint4 q;
    q.x = rbf(a.x) | (rbf(a.y) << 16);
    q.y = rbf(a.z) | (rbf(a.w) << 16);
    q.z = rbf(b.x) | (rbf(b.y) << 16);
    q.w = rbf(b.z) | (rbf(b.w) << 16);
    return q;
}

#define MFMA(av,bv,acc) __builtin_amdgcn_mfma_f32_32x32x16_bf16(av,bv,acc,0,0,0)

// Fully fused: detect + SHA + W-convert + GEMM + bias, one dispatch, no ws.
// Grid 256 blocks (1/CU) x 256 threads (4 waves).
// Block (bm = bid>>1, nh = bid&1): C[bm*128 .. +128][nh*512 .. +512].
// LDS: A fragments 64KB (resident, full K) + B double-buffer 2x32KB = 128KiB.
__global__ __launch_bounds__(256, 1) void fused_kernel(const uint32_t* __restrict__ ids32,
                                                       const float* __restrict__ W,
                                                       const float* __restrict__ bias,
                                                       float* __restrict__ out) {
    __shared__ uint4 Albuf[4096];   // A: [4 g][16 kf][64 l] x 16B = 64KB
    __shared__ uint4 Blbuf[4096];   // B: 2 x [4 g][8 ks][64 l] x 16B = 64KB
    uint32_t* redf = (uint32_t*)(Blbuf + 2048);  // aliased in buf1: last read
                                                 // strictly before buf1's first write

    const int bid = blockIdx.x;
    const int bm = bid >> 1;
    const int nb0 = (bid & 1) * 512;
    const int tid = (int)threadIdx.x;
    const int wv = tid >> 6, lane = tid & 63, lrow = lane & 31, lh = lane >> 5;
    const int wm = (wv >> 1) * 64, wn = (wv & 1) * 64;
    const int lga = (wv >> 1) * 2, lgb = (wv & 1) * 2;
    const int rr = tid >> 1;          // local token row / B-staging row (0..127)
    const uint32_t st = tid & 1;      // SHA state id / B col-half
    const int ag = rr >> 5, aslot = rr & 31;

    float4 stgA[16], stgB[16];        // statically-indexed only (rule #20)

#define ISSUE(dst, cc) do {                                                        \
    const float4* ws_ = reinterpret_cast<const float4*>(                           \
        W + (size_t)(nb0 + ((cc) >> 1) * 128 + rr) * EMB + ((cc) & 1) * 128 + (int)st * 64); \
    _Pragma("unroll") for (int i_ = 0; i_ < 16; ++i_) dst[i_] = ws_[i_]; } while (0)

#define WRITEB(src, cc) do {                                                       \
    uint4* bb_ = Blbuf + ((cc) & 1) * 2048 + (ag * 8) * 64 + aslot;                \
    _Pragma("unroll") for (int q_ = 0; q_ < 4; ++q_) {                             \
        uint4 h0_ = pack8(src[q_ * 4 + 0], src[q_ * 4 + 1]);                       \
        uint4 h1_ = pack8(src[q_ * 4 + 2], src[q_ * 4 + 3]);                       \
        bb_[((int)st * 4 + q_) * 64]      = h0_;                                   \
        bb_[((int)st * 4 + q_) * 64 + 32] = h1_; } } while (0)

#define MFMA_CHUNK(cc) do {                                                        \
    const uint4* bb_ = Blbuf + ((cc) & 1) * 2048;                                  \
    _Pragma("unroll") for (int ks_ = 0; ks_ < 8; ++ks_) {                          \
        bf16x8 av0 = *reinterpret_cast<const bf16x8*>(&Albuf[(lga * 16 + ((cc) & 1) * 8 + ks_) * 64 + lane]); \
        bf16x8 av1 = *reinterpret_cast<const bf16x8*>(&Albuf[((lga + 1) * 16 + ((cc) & 1) * 8 + ks_) * 64 + lane]); \
        bf16x8 bv0 = *reinterpret_cast<const bf16x8*>(&bb_[(lgb * 8 + ks_) * 64 + lane]); \
        bf16x8 bv1 = *reinterpret_cast<const bf16x8*>(&bb_[((lgb + 1) * 8 + ks_) * 64 + lane]); \
        acc00 = MFMA(av0, bv0, acc00); acc01 = MFMA(av0, bv1, acc01);              \
        acc10 = MFMA(av1, bv0, acc10); acc11 = MFMA(av1, bv1, acc11); } } while (0)

#define STORE_SUB(ss, bj0_, bj1_) do {                                             \
    const int n0s_ = nb0 + (ss) * 128 + wn;                                        \
    _Pragma("unroll") for (int r_ = 0; r_ < 16; ++r_) {                            \
        const int rowl_ = (r_ & 3) + 8 * (r_ >> 2) + 4 * lh;                       \
        const size_t o0_ = (size_t)(bm * 128 + wm + rowl_) * HID;                  \
        const size_t o1_ = o0_ + 32 * HID;                                         \
        out[o0_ + n0s_ + lrow]      = acc00[r_] + bj0_;                            \
        out[o0_ + n0s_ + 32 + lrow] = acc01[r_] + bj1_;                            \
        out[o1_ + n0s_ + lrow]      = acc10[r_] + bj0_;                            \
        out[o1_ + n0s_ + 32 + lrow] = acc11[r_] + bj1_; }                          \
    acc00 = (f32x16)(0.0f); acc01 = (f32x16)(0.0f);                                \
    acc10 = (f32x16)(0.0f); acc11 = (f32x16)(0.0f); } while (0)

    // ---- issue chunk0 W loads first (latency hides under detect + SHA) ----
    ISSUE(stgA, 0);

    // ---- detect int64 vs int32 layout (first 8KB; odd words all-zero => int64) ----
    {
        const uint4* ids4 = reinterpret_cast<const uint4*>(ids32);
        uint4 da = ids4[tid], db = ids4[tid + 256];
        uint32_t z = da.y | da.w | db.y | db.w;
        unsigned long long m = __ballot(z != 0u);
        if (lane == 0) redf[wv] = (m != 0ull) ? 1u : 0u;
    }
    __syncthreads();
    const bool is64 = (redf[0] | redf[1] | redf[2] | redf[3]) == 0u;

    const int tok = bm * 128 + rr;
    const uint32_t v = is64 ? ids32[2 * tok] : ids32[tok];

    // ---- branchless decimal message (proven R4/R5) ----
    const uint32_t q4 = __umulhi(v, 0xD1B71759u) >> 13;
    const uint32_t r4 = v - q4 * 10000u;
    const uint32_t q3 = __umulhi(r4, 0x10624DD3u) >> 6;
    const uint32_t r3 = r4 - q3 * 1000u;
    const uint32_t q2 = __umulhi(r3, 0x51EB851Fu) >> 5;
    const uint32_t r2 = r3 - q2 * 100u;
    const uint32_t q1 = __umulhi(r2, 0xCCCCCCCDu) >> 3;
    const uint32_t q0 = r2 - q1 * 10u;
    const uint32_t nd = v >= 10000u ? 5u : v >= 1000u ? 4u : v >= 100u ? 3u
                         : v >= 10u ? 2u : 1u;
    uint64_t M = ((uint64_t)(q4 + '0') << 56) | ((uint64_t)(q3 + '0') << 48) |
                 ((uint64_t)(q2 + '0') << 40) | ((uint64_t)(q1 + '0') << 32) |
                 ((uint64_t)(q0 + '0') << 24) | ((uint64_t)0x80u << 16);
    M <<= 8u * (5u - nd);

    uint32_t w0 = (uint32_t)(M >> 32), w1 = (uint32_t)M;
    uint32_t w2 = 0, w3 = 0, w4 = 0, w5 = 0, w6 = 0, w7 = 0;
    uint32_t w8 = 0, w9 = 0, w10 = 0, w11 = 0, w12 = 0, w13 = 0, w14 = 0;
    uint32_t w15 = nd * 8u;

    // ---- ONE SHA state per thread (even=SHA-256, odd=SHA-224) ----
    uint32_t sa = st ? 0xc1059ed8u : 0x6a09e667u;
    uint32_t sb = st ? 0x367cd507u : 0xbb67ae85u;
    uint32_t sc = st ? 0x3070dd17u : 0x3c6ef372u;
    uint32_t sd = st ? 0xf70e5939u : 0xa54ff53au;
    uint32_t se = st ? 0xffc00b31u : 0x510e527fu;
    uint32_t sf = st ? 0x68581511u : 0x9b05688cu;
    uint32_t sg = st ? 0x64f98fa7u : 0x1f83d9abu;
    uint32_t sh = st ? 0xbefa4fa4u : 0x5be0cd19u;

    // rounds 0-15
    RND1(0x428a2f98u, w0);  RND1(0x71374491u, w1);  RND1(0xb5c0fbcfu, w2);
    RND1(0xe9b5dba5u, w3);  RND1(0x3956c25bu, w4);  RND1(0x59f111f1u, w5);
    RND1(0x923f82a4u, w6);  RND1(0xab1c5ed5u, w7);  RND1(0xd807aa98u, w8);
    RND1(0x12835b01u, w9);  RND1(0x243185beu, w10); RND1(0x550c7dc3u, w11);
    RND1(0x72be5d74u, w12); RND1(0x80deb1feu, w13); RND1(0x9bdc06a7u, w14);
    RND1(0xc19bf174u, w15);
    // rounds 16-31
    WSXS(w0,w1,w9,w14);    RND1(0xe49b69c1u, w0);
    WSXS(w1,w2,w10,w15);   RND1(0xefbe4786u, w1);
    WSXS(w2,w3,w11,w0);    RND1(0x0fc19dc6u, w2);
    WSXS(w3,w4,w12,w1);    RND1(0x240ca1ccu, w3);
    WSXS(w4,w5,w13,w2);    RND1(0x2de92c6fu, w4);
    WSXS(w5,w6,w14,w3);    RND1(0x4a7484aau, w5);
    WSXS(w6,w7,w15,w4);    RND1(0x5cb0a9dcu, w6);
    WSXS(w7,w8,w0,w5);     RND1(0x76f988dau, w7);
    WSXS(w8,w9,w1,w6);     RND1(0x983e5152u, w8);
    WSXS(w9,w10,w2,w7);    RND1(0xa831c66du, w9);
    WSXS(w10,w11,w3,w8);   RND1(0xb00327c8u, w10);
    WSXS(w11,w12,w4,w9);   RND1(0xbf597fc7u, w11);
    WSXS(w12,w13,w5,w10);  RND1(0xc6e00bf3u, w12);
    WSXS(w13,w14,w6,w11);  RND1(0xd5a79147u, w13);
    WSXS(w14,w15,w7,w12);  RND1(0x06ca6351u, w14);
    WSXS(w15,w0,w8,w13);   RND1(0x14292967u, w15);
    // rounds 32-47
    WSXS(w0,w1,w9,w14);    RND1(0x27b70a85u, w0);
    WSXS(w1,w2,w10,w15);   RND1(0x2e1b2138u, w1);
    WSXS(w2,w3,w11,w0);    RND1(0x4d2c6dfcu, w2);
    WSXS(w3,w4,w12,w1);    RND1(0x53380d13u, w3);
    WSXS(w4,w5,w13,w2);    RND1(0x650a7354u, w4);
    WSXS(w5,w6,w14,w3);    RND1(0x766a0abbu, w5);
    WSXS(w6,w7,w15,w4);    RND1(0x81c2c92eu, w6);
    WSXS(w7,w8,w0,w5);     RND1(0x92722c85u, w7);
    WSXS(w8,w9,w1,w6);     RND1(0xa2bfe8a1u, w8);
    WSXS(w9,w10,w2,w7);    RND1(0xa81a664bu, w9);
    WSXS(w10,w11,w3,w8);   RND1(0xc24b8b70u, w10);
    WSXS(w11,w12,w4,w9);   RND1(0xc76c51a3u, w11);
    WSXS(w12,w13,w5,w10);  RND1(0xd192e819u, w12);
    WSXS(w13,w14,w6,w11);  RND1(0xd6990624u, w13);
    WSXS(w14,w15,w7,w12);  RND1(0xf40e3585u, w14);
    WSXS(w15,w0,w8,w13);   RND1(0x106aa070u, w15);
    // rounds 48-63
    WSXS(w0,w1,w9,w14);    RND1(0x19a4c116u, w0);
    WSXS(w1,w2,w10,w15);   RND1(0x1e376c08u, w1);
    WSXS(w2,w3,w11,w0);    RND1(0x2748774cu, w2);
    WSXS(w3,w4,w12,w1);    RND1(0x34b0bcb5u, w3);
    WSXS(w4,w5,w13,w2);    RND1(0x391c0cb3u, w4);
    WSXS(w5,w6,w14,w3);    RND1(0x4ed8aa4au, w5);
    WSXS(w6,w7,w15,w4);    RND1(0x5b9cca4fu, w6);
    WSXS(w7,w8,w0,w5);     RND1(0x682e6ff3u, w7);
    WSXS(w8,w9,w1,w6);     RND1(0x748f82eeu, w8);
    WSXS(w9,w10,w2,w7);    RND1(0x78a5636fu, w9);
    WSXS(w10,w11,w3,w8);   RND1(0x84c87814u, w10);
    WSXS(w11,w12,w4,w9);   RND1(0x8cc70208u, w11);
    WSXS(w12,w13,w5,w10);  RND1(0x90befffau, w12);
    WSXS(w13,w14,w6,w11);  RND1(0xa4506cebu, w13);
    WSXS(w14,w15,w7,w12);  RND1(0xbef9a3f7u, w14);
    WSXS(w15,w0,w8,w13);   RND1(0xc67178f2u, w15);

    const uint32_t hv = ((st ? 0xc1059ed8u : 0x6a09e667u) + sa) >> 24;
    const uint32_t hvo = __shfl_xor(hv, 1);              // partner's digest byte
    const uint32_t hv1 = st ? hvo : hv;                  // sha256 byte
    const uint32_t hv2 = st ? hv : hvo;                  // sha224 byte

    // ---- A fragments to LDS: even thread kf 0..7 (k<128), odd kf 8..15 ----
    {
        uint32_t val = (hv1 + (st ? ((hv2 << 7) & 255u) : 0u)) & 255u;
        const int kfb = (int)st * 8;
#define PAIR(dst) { uint32_t lo_ = val; uint32_t hi_ = (val + hv2) & 255u;        \
                    val = (hi_ + hv2) & 255u;                                     \
                    dst = (__float_as_uint((float)lo_) >> 16) |                   \
                          (__float_as_uint((float)hi_) & 0xFFFF0000u); }
#pragma unroll
        for (int q = 0; q < 8; ++q) {
            uint32_t c0_, c1_, c2_, c3_, c4_, c5_, c6_, c7_;
            PAIR(c0_); PAIR(c1_); PAIR(c2_); PAIR(c3_);
            PAIR(c4_); PAIR(c5_); PAIR(c6_); PAIR(c7_);
            uint4 qa; qa.x = c0_; qa.y = c1_; qa.z = c2_; qa.w = c3_;
            uint4 qb; qb.x = c4_; qb.y = c5_; qb.z = c6_; qb.w = c7_;
            Albuf[(ag * 16 + kfb + q) * 64 + aslot]      = qa;   // k-half 0
            Albuf[(ag * 16 + kfb + q) * 64 + aslot + 32] = qb;   // k-half 1
        }
#undef PAIR
    }

    WRITEB(stgA, 0);    // chunk0 -> buf0 (loads long since landed)
    ISSUE(stgB, 1);     // chunk1 loads in flight across the barrier

    // biases for the 4 n-subtiles (hoisted, static names)
    const float b00 = bias[nb0 +   0 + wn + lrow], b01 = bias[nb0 +   0 + wn + 32 + lrow];
    const float b10 = bias[nb0 + 128 + wn + lrow], b11 = bias[nb0 + 128 + wn + 32 + lrow];
    const float b20 = bias[nb0 + 256 + wn + lrow], b21 = bias[nb0 + 256 + wn + 32 + lrow];
    const float b30 = bias[nb0 + 384 + wn + lrow], b31 = bias[nb0 + 384 + wn + 32 + lrow];

    f32x16 acc00 = (f32x16)(0.0f), acc01 = (f32x16)(0.0f);
    f32x16 acc10 = (f32x16)(0.0f), acc11 = (f32x16)(0.0f);

    __syncthreads();    // A complete + B chunk0 complete

    // ---- 8-chunk main loop (chunk c = sub*2 + ph), 1 barrier per chunk ----
    ISSUE(stgA, 2);  MFMA_CHUNK(0);                         WRITEB(stgB, 1); __syncthreads();
    ISSUE(stgB, 3);  MFMA_CHUNK(1); STORE_SUB(0, b00, b01); WRITEB(stgA, 2); __syncthreads();
    ISSUE(stgA, 4);  MFMA_CHUNK(2);                         WRITEB(stgB, 3); __syncthreads();
    ISSUE(stgB, 5);  MFMA_CHUNK(3); STORE_SUB(1, b10, b11); WRITEB(stgA, 4); __syncthreads();
    ISSUE(stgA, 6);  MFMA_CHUNK(4);                         WRITEB(stgB, 5); __syncthreads();
    ISSUE(stgB, 7);  MFMA_CHUNK(5); STORE_SUB(2, b20, b21); WRITEB(stgA, 6); __syncthreads();
                     MFMA_CHUNK(6);                         WRITEB(stgB, 7); __syncthreads();
                     MFMA_CHUNK(7); STORE_SUB(3, b30, b31);

#undef ISSUE
#undef WRITEB
#undef MFMA_CHUNK
#undef STORE_SUB
}

extern "C" void kernel_launch(void* const* d_in, const int* in_sizes, int n_in,
                              void* d_out, int out_size, void* d_ws, size_t ws_size,
                              hipStream_t stream) {
    const uint32_t* ids32 = (const uint32_t*)d_in[0];
    const float* W = (const float*)d_in[1];
    const float* bias = (const float*)d_in[2];
    float* out = (float*)d_out;
    (void)d_ws; (void)ws_size; (void)in_sizes; (void)n_in; (void)out_size;

    fused_kernel<<<256, 256, 0, stream>>>(ids32, W, bias, out);
}